// Round 26
// baseline (332.003 us; speedup 1.0000x reference)
//
#include <hip/hip_runtime.h>
#include <math.h>

namespace {
constexpr int NB   = 256;          // graphs
constexpr int EPG  = 8192;         // edges per graph
constexpr int ETOT = NB * EPG;     // 2,097,152
}

// ============================================================================
// mono v5: v4 with pool0 compaction from REGISTER-held edges (epk[8] stays
// live from ph1) — single global edge pass AND fully parallel compaction.
// ============================================================================
__global__ __launch_bounds__(1024)
void mono(const float* __restrict__ x,
          const int* __restrict__ esrc, const int* __restrict__ edst,
          const float* __restrict__ c1Wr, const float* __restrict__ c1Wl,
          const float* __restrict__ c1b,
          const float* __restrict__ cWr, const float* __restrict__ cWl,
          const float* __restrict__ cb,
          const float* __restrict__ pwr, const float* __restrict__ pwl,
          const float* __restrict__ pb,
          const float* __restrict__ l1W, const float* __restrict__ l1b,
          const float* __restrict__ l2W, const float* __restrict__ l2b,
          float* __restrict__ out)
{
  __shared__ float zlds[512 * 64];                        // 128 KB
  __shared__ unsigned short csrbuf[EPG];                  // 16 KB
  __shared__ __align__(16) unsigned long long u2[512];    // 4 KB
  __shared__ __align__(16) float wpf[2048];               // 8 KB
  __shared__ float xsl[384];                              // 1.5 KB (JK concat)
  __shared__ int scnt;
  unsigned int* hist  = reinterpret_cast<unsigned int*>(u2);   // [0..512)
  unsigned int* start = hist + 512;                            // [512..1024)
  unsigned int* curp  = reinterpret_cast<unsigned int*>(wpf);  // scatter cursor
  const int g = blockIdx.x, t = threadIdx.x;
  const int gbase = g * 512, ebase = g * EPG;
  const int lane = t & 63, w = t >> 6;                    // 16 waves
  const int ndbase = w * 32;

  auto stage_chunk = [&](int c, int p) {
    const int xb  = p ? 8192  : 0;
    const int wrO = p ? 18432 : 16384;
    const int wlO = p ? 22528 : 20480;
    #pragma unroll
    for (int i = 0; i < 2; ++i) {            // x: 512 rows x 16 k = 2048x16B
      const int slot = t + i * 1024;
      const int r = slot >> 2, q = slot & 3;
      const float* gp = &x[(size_t)(gbase + r) * 160 + c * 16 + q * 4];
      float* lp = zlds + xb + (size_t)(i * 1024 + w * 64) * 4;
      __builtin_amdgcn_global_load_lds(
          (const __attribute__((address_space(1))) unsigned int*)gp,
          (__attribute__((address_space(3))) unsigned int*)lp, 16, 0, 0);
    }
    {
      const float* gp = &c1Wr[c * 1024 + t];
      float* lp = zlds + wrO + (size_t)(w * 64);
      __builtin_amdgcn_global_load_lds(
          (const __attribute__((address_space(1))) unsigned int*)gp,
          (__attribute__((address_space(3))) unsigned int*)lp, 4, 0, 0);
    }
    {
      const float* gp = &c1Wl[c * 1024 + t];
      float* lp = zlds + wlO + (size_t)(w * 64);
      __builtin_amdgcn_global_load_lds(
          (const __attribute__((address_space(1))) unsigned int*)gp,
          (__attribute__((address_space(3))) unsigned int*)lp, 4, 0, 0);
    }
  };

  // ---- ph1: CSR build (single global edge pass; edges held in registers) ----
  if (t < 512) hist[t] = 0;
  if (t == 0) scnt = 0;
  __syncthreads();
  stage_chunk(0, 0);
  unsigned int epk[8];                     // live until ph6 compaction
  #pragma unroll
  for (int i = 0; i < 8; ++i) {
    const int e = ebase + t + i * 1024;
    const int sl = esrc[e] - gbase;
    const int dl = edst[e] - gbase;
    epk[i] = (unsigned int)sl | ((unsigned int)dl << 16);
  }
  #pragma unroll
  for (int i = 0; i < 8; ++i)
    atomicAdd(&hist[epk[i] >> 16], 1u);
  __syncthreads();
  {
    unsigned int v = 0;
    if (t < 512) {
      v = hist[t];
      #pragma unroll
      for (int off = 1; off < 64; off <<= 1) {
        const unsigned int up = __shfl_up(v, off);
        if (lane >= off) v += up;
      }
      if (lane == 63)
        reinterpret_cast<unsigned int*>(wpf)[1024 + w] = v;
    }
    __syncthreads();
    if (t < 512) {
      unsigned int off = 0;
      for (int i = 0; i < w; ++i)
        off += reinterpret_cast<unsigned int*>(wpf)[1024 + i];
      const unsigned int st = off + v - hist[t];
      start[t] = st;
      curp[t]  = st;
    }
    __syncthreads();
    #pragma unroll
    for (int i = 0; i < 8; ++i) {
      const unsigned int pr = epk[i];
      const unsigned int pos = atomicAdd(&curp[pr >> 16], 1u);
      csrbuf[pos] = (unsigned short)(pr & 0xffff);
    }
  }
  __syncthreads();
  // ---- ph2: GEMM1, 2-phase pipelined ----
  float zacc[32], xla[32];
  #pragma unroll
  for (int i = 0; i < 32; ++i) { zacc[i] = 0.f; xla[i] = 0.f; }
  #pragma unroll 1
  for (int c = 0; c < 10; ++c) {
    if (c < 9) stage_chunk(c + 1, (c + 1) & 1);
    const int p   = c & 1;
    const int xb  = p ? 8192  : 0;
    const int wrO = p ? 18432 : 16384;
    const int wlO = p ? 22528 : 20480;
    #pragma unroll 1
    for (int k4 = 0; k4 < 4; ++k4) {
      const int kb = k4 * 4;
      const float wr0 = zlds[wrO + (kb+0)*64 + lane], wr1 = zlds[wrO + (kb+1)*64 + lane],
                  wr2 = zlds[wrO + (kb+2)*64 + lane], wr3 = zlds[wrO + (kb+3)*64 + lane];
      const float wl0 = zlds[wlO + (kb+0)*64 + lane], wl1 = zlds[wlO + (kb+1)*64 + lane],
                  wl2 = zlds[wlO + (kb+2)*64 + lane], wl3 = zlds[wlO + (kb+3)*64 + lane];
      #pragma unroll
      for (int i = 0; i < 32; ++i) {
        const float4 xv = *reinterpret_cast<const float4*>(
            &zlds[xb + (ndbase + i) * 16 + kb]);
        float za = zacc[i], xa = xla[i];
        za = fmaf(xv.x, wr0, za); za = fmaf(xv.y, wr1, za);
        za = fmaf(xv.z, wr2, za); za = fmaf(xv.w, wr3, za);
        xa = fmaf(xv.x, wl0, xa); xa = fmaf(xv.y, wl1, xa);
        xa = fmaf(xv.z, wl2, xa); xa = fmaf(xv.w, wl3, xa);
        zacc[i] = za; xla[i] = xa;
      }
    }
    __syncthreads();
  }
  #pragma unroll
  for (int i = 0; i < 32; ++i)
    zlds[(ndbase + i) * 64 + lane] = zacc[i];             // z1
  __syncthreads();
  // dual-node 8-deep CSR gather over LDS (per-node order = 4-chunks + tail)
  auto gather_pair = [&](float* dstacc, const float* bias_p, float& psum) {
    const float bv = bias_p[lane];
    #pragma unroll 1
    for (int i = 0; i < 16; ++i) {
      const int ndA = ndbase + i, ndB = ndbase + 16 + i;
      const unsigned int sA = start[ndA], dA = hist[ndA];
      const unsigned int sB = start[ndB], dB = hist[ndB];
      float aA0=0.f,aA1=0.f,aA2=0.f,aA3=0.f;
      float aB0=0.f,aB1=0.f,aB2=0.f,aB3=0.f;
      unsigned int jA = 0, jB = 0;
      while (jA + 4 <= dA && jB + 4 <= dB) {
        const int iA0 = csrbuf[sA+jA],   iA1 = csrbuf[sA+jA+1],
                  iA2 = csrbuf[sA+jA+2], iA3 = csrbuf[sA+jA+3];
        const int iB0 = csrbuf[sB+jB],   iB1 = csrbuf[sB+jB+1],
                  iB2 = csrbuf[sB+jB+2], iB3 = csrbuf[sB+jB+3];
        const float vA0 = zlds[iA0*64+lane], vA1 = zlds[iA1*64+lane];
        const float vA2 = zlds[iA2*64+lane], vA3 = zlds[iA3*64+lane];
        const float vB0 = zlds[iB0*64+lane], vB1 = zlds[iB1*64+lane];
        const float vB2 = zlds[iB2*64+lane], vB3 = zlds[iB3*64+lane];
        aA0 += vA0; aA1 += vA1; aA2 += vA2; aA3 += vA3;
        aB0 += vB0; aB1 += vB1; aB2 += vB2; aB3 += vB3;
        jA += 4; jB += 4;
      }
      for (; jA + 4 <= dA; jA += 4) {
        aA0 += zlds[csrbuf[sA+jA]*64+lane];   aA1 += zlds[csrbuf[sA+jA+1]*64+lane];
        aA2 += zlds[csrbuf[sA+jA+2]*64+lane]; aA3 += zlds[csrbuf[sA+jA+3]*64+lane];
      }
      for (; jB + 4 <= dB; jB += 4) {
        aB0 += zlds[csrbuf[sB+jB]*64+lane];   aB1 += zlds[csrbuf[sB+jB+1]*64+lane];
        aB2 += zlds[csrbuf[sB+jB+2]*64+lane]; aB3 += zlds[csrbuf[sB+jB+3]*64+lane];
      }
      for (; jA < dA; ++jA) aA0 += zlds[csrbuf[sA+jA]*64+lane];
      for (; jB < dB; ++jB) aB0 += zlds[csrbuf[sB+jB]*64+lane];
      float vA = ((aA0+aA1)+(aA2+aA3)) / (float)(dA > 0 ? dA : 1) + xla[i] + bv;
      float vB = ((aB0+aB1)+(aB2+aB3)) / (float)(dB > 0 ? dB : 1) + xla[16+i] + bv;
      vA = fmaxf(vA, 0.f);
      vB = fmaxf(vB, 0.f);
      dstacc[i] = vA; dstacc[16+i] = vB;
      psum += vA + vB;
    }
  };
  // ---- ph3: gather1 -> x1 ----
  {
    float psum = 0.f;
    gather_pair(zacc, c1b, psum);
    __syncthreads();
    #pragma unroll
    for (int i = 0; i < 32; ++i)
      zlds[(ndbase + i) * 64 + lane] = zacc[i];           // x1
    wpf[w * 64 + lane] = psum;
    __syncthreads();
    if (t < 64) {
      float s = 0.f;
      #pragma unroll
      for (int ww = 0; ww < 16; ++ww) s += wpf[ww*64 + t];
      xsl[0 + t] = s * (1.f/512.f);
    }
  }
  // ---- ph4: GEMM2 ----
  #pragma unroll
  for (int i = 0; i < 32; ++i) { zacc[i] = 0.f; xla[i] = 0.f; }
  {
    float* w_r = wpf;
    float* w_l = wpf + 1024;
    #pragma unroll 1
    for (int c = 0; c < 4; ++c) {
      __syncthreads();
      w_r[t] = cWr[c * 1024 + t];
      w_l[t] = cWl[c * 1024 + t];
      __syncthreads();
      #pragma unroll 1
      for (int k4 = 0; k4 < 4; ++k4) {
        const int kb = k4 * 4;
        const float wr0 = w_r[(kb+0)*64 + lane], wr1 = w_r[(kb+1)*64 + lane],
                    wr2 = w_r[(kb+2)*64 + lane], wr3 = w_r[(kb+3)*64 + lane];
        const float wl0 = w_l[(kb+0)*64 + lane], wl1 = w_l[(kb+1)*64 + lane],
                    wl2 = w_l[(kb+2)*64 + lane], wl3 = w_l[(kb+3)*64 + lane];
        #pragma unroll
        for (int i = 0; i < 32; ++i) {
          const float4 xv = *reinterpret_cast<const float4*>(
              &zlds[(ndbase + i) * 64 + c * 16 + kb]);
          float za = zacc[i], xa = xla[i];
          za = fmaf(xv.x, wr0, za); za = fmaf(xv.y, wr1, za);
          za = fmaf(xv.z, wr2, za); za = fmaf(xv.w, wr3, za);
          xa = fmaf(xv.x, wl0, xa); xa = fmaf(xv.y, wl1, xa);
          xa = fmaf(xv.z, wl2, xa); xa = fmaf(xv.w, wl3, xa);
          zacc[i] = za; xla[i] = xa;
        }
      }
    }
  }
  __syncthreads();
  #pragma unroll
  for (int i = 0; i < 32; ++i)
    zlds[(ndbase + i) * 64 + lane] = zacc[i];             // z2
  __syncthreads();
  // ---- ph5: gather2 -> x2 ----
  {
    float psum = 0.f;
    gather_pair(zacc, cb, psum);
    __syncthreads();
    #pragma unroll
    for (int i = 0; i < 32; ++i)
      zlds[(ndbase + i) * 64 + lane] = zacc[i];           // x2
    wpf[w * 64 + lane] = psum;
    __syncthreads();
    if (t < 64) {
      float s = 0.f;
      #pragma unroll
      for (int ww = 0; ww < 16; ++ww) s += wpf[ww*64 + t];
      xsl[64 + t] = s * (1.f/512.f);
    }
    __syncthreads();
  }
  // ---- ph6: pool0 ----
  {
    float* zs     = wpf;
    float* swl    = wpf + 512;
    float* sscore = wpf + 1024;
    const float pwrv = pwr[lane], pwlv = pwl[lane];
    for (int nd = w; nd < 512; nd += 16) {
      const float v = zlds[nd*64 + lane];
      float a = v * pwrv, b = v * pwlv;
      #pragma unroll
      for (int off = 32; off > 0; off >>= 1) {
        a += __shfl_xor(a, off);
        b += __shfl_xor(b, off);
      }
      if (lane == 0) { zs[nd] = a; swl[nd] = b; }
    }
    __syncthreads();
    if (t < 512) {
      const unsigned int s = start[t], d = hist[t];
      float a0 = 0.f, a1 = 0.f, a2 = 0.f, a3 = 0.f;
      unsigned int j = 0;
      for (; j + 4 <= d; j += 4) {
        a0 += zs[csrbuf[s+j]];   a1 += zs[csrbuf[s+j+1]];
        a2 += zs[csrbuf[s+j+2]]; a3 += zs[csrbuf[s+j+3]];
      }
      for (; j < d; ++j) a0 += zs[csrbuf[s+j]];
      sscore[t] = ((a0+a1)+(a2+a3)) / fmaxf((float)d, 1.f) + pb[0] + swl[t];
    }
    __syncthreads();                 // zs/swl dead
    unsigned long long k = 0ull;
    if (t < 512) {
      unsigned int u = __float_as_uint(sscore[t]);
      u = (u & 0x80000000u) ? ~u : (u | 0x80000000u);
      k = ((unsigned long long)u << 32) | (unsigned int)(~(unsigned int)t);
    }
    for (int kk = 2; kk <= 512; kk <<= 1) {
      for (int j = kk >> 1; j > 0; j >>= 1) {
        if (j >= 64) {
          if (t < 512) u2[t] = k;
          __syncthreads();
          unsigned long long kp = 0ull;
          if (t < 512) kp = u2[t ^ j];
          __syncthreads();
          if (t < 512) {
            const bool keep_max = (((t & kk) == 0) == ((t & j) == 0));
            k = keep_max ? (k >= kp ? k : kp) : (k >= kp ? kp : k);
          }
        } else if (t < 512) {
          const unsigned int lo = __shfl_xor((unsigned int)k, j);
          const unsigned int hi = __shfl_xor((unsigned int)(k >> 32), j);
          const unsigned long long kp = ((unsigned long long)hi << 32) | lo;
          const bool keep_max = (((t & kk) == 0) == ((t & j) == 0));
          k = keep_max ? (k >= kp ? k : kp) : (k >= kp ? kp : k);
        }
      }
    }
    if (t < 512) u2[t] = k;
    __syncthreads();
    unsigned long long* keys = u2;
    short* np = reinterpret_cast<short*>(wpf);   // wpf[0..256) floats; zs dead
    if (t < 512) np[t] = -1;
    __syncthreads();
    if (t < 57)
      np[(int)(~(unsigned int)(keys[t] & 0xffffffffull))] = (short)t;
    __syncthreads();
    float xr[4];
    int nr = 0;
    for (int r = w * 4; r < w * 4 + 4 && r < 57; ++r) {
      const int old = (int)(~(unsigned int)(keys[r] & 0xffffffffull));
      xr[nr++] = zlds[old*64 + lane] * tanhf(sscore[old]);
    }
    if (t < 64) wpf[512 + t] = 0.f;  // deg (swl region dead)
    if (t == 0) scnt = 0;
    __syncthreads();
    nr = 0;
    for (int r = w * 4; r < w * 4 + 4 && r < 57; ++r)
      zlds[r*64 + lane] = xr[nr++];  // X57
    // compaction from REGISTER-held edges: parallel, zero extra reads
    unsigned int* eb = reinterpret_cast<unsigned int*>(zlds + 16384);
    #pragma unroll
    for (int i = 0; i < 8; ++i) {
      const unsigned int pr = epk[i];
      const short ns = np[pr & 0xffff], nd2 = np[pr >> 16];
      if (ns >= 0 && nd2 >= 0) {
        const int slot = atomicAdd(&scnt, 1);
        eb[slot] = (unsigned int)ns | ((unsigned int)nd2 << 16);
        atomicAdd(&wpf[512 + nd2], 1.f);
      }
    }
    __syncthreads();
  }
  const int m0 = scnt;
  // ---- ph7: tail ----
  float* X   = zlds;
  float* Z   = zlds + 4096;
  float* ACC = zlds + 8192;
  float* deg = wpf + 512;
  unsigned int* eb  = reinterpret_cast<unsigned int*>(zlds + 16384);
  unsigned int* eb1 = reinterpret_cast<unsigned int*>(zlds + 24576);

  auto conv57 = [&](int n, const unsigned int* edges, int m,
                    const float* Wr, const float* Wl, const float* bias,
                    int xs_off) {
    float* Wfull = zlds + 12288;
    for (int i = t; i < n*64; i += 1024) ACC[i] = 0.f;
    #pragma unroll
    for (int i = 0; i < 4; ++i) Wfull[t + i*1024] = Wr[t + i*1024];
    __syncthreads();
    for (int r = w; r < n; r += 16) {
      float za = 0.f;
      for (int k = 0; k < 64; ++k)
        za = fmaf(X[r*64 + k], Wfull[k*64 + lane], za);
      Z[r*64 + lane] = za;
    }
    __syncthreads();
    for (int e = w; e < m; e += 16) {
      const unsigned int pr = edges[e];
      atomicAdd(&ACC[(pr >> 16)*64 + lane], Z[(pr & 0xffff)*64 + lane]);
    }
    #pragma unroll
    for (int i = 0; i < 4; ++i) Wfull[t + i*1024] = Wl[t + i*1024];
    __syncthreads();
    for (int i = t; i < n*64; i += 1024) {
      const int r = i >> 6, f = i & 63;
      Z[i] = ACC[i] / fmaxf(deg[r], 1.f) + bias[f];
    }
    __syncthreads();
    float psum = 0.f;
    for (int r = w; r < n; r += 16) {
      float za = Z[r*64 + lane];
      for (int k = 0; k < 64; ++k)
        za = fmaf(X[r*64 + k], Wfull[k*64 + lane], za);
      za = fmaxf(za, 0.f);
      X[r*64 + lane] = za;
      psum += za;
    }
    ACC[w*64 + lane] = psum;
    __syncthreads();
    if (t < 64) {
      float s = 0.f;
      #pragma unroll
      for (int ww = 0; ww < 16; ++ww) s += ACC[ww*64 + t];
      xsl[xs_off + t] = s / (float)n;
    }
    __syncthreads();
  };

  conv57(57, eb, m0, cWr + 4096, cWl + 4096, cb + 64, 128);
  conv57(57, eb, m0, cWr + 8192, cWl + 8192, cb + 128, 192);

  // ---- pool1: 57 -> 7 ----
  {
    float* zs1 = wpf + 1536;
    float* sw1 = wpf + 1600;
    float* ss1 = wpf + 1664;
    const float pwrv = pwr[64 + lane], pwlv = pwl[64 + lane];
    for (int r = w; r < 57; r += 16) {
      float a = X[r*64 + lane] * pwrv, b = X[r*64 + lane] * pwlv;
      #pragma unroll
      for (int off = 32; off > 0; off >>= 1) {
        a += __shfl_xor(a, off);
        b += __shfl_xor(b, off);
      }
      if (lane == 0) { zs1[r] = a; sw1[r] = b; }
    }
    if (t >= 64 && t < 128) ACC[t - 64] = 0.f;
    __syncthreads();
    for (int e = t; e < m0; e += 1024) {
      const unsigned int pr = eb[e];
      atomicAdd(&ACC[pr >> 16], zs1[pr & 0xffff]);
    }
    __syncthreads();
    if (t < 57) ss1[t] = ACC[t] / fmaxf(deg[t], 1.f) + pb[1] + sw1[t];
    __syncthreads();
    if (w == 0) {
      unsigned long long k1 = 0ull;
      if (lane < 57) {
        unsigned int u = __float_as_uint(ss1[lane]);
        u = (u & 0x80000000u) ? ~u : (u | 0x80000000u);
        k1 = ((unsigned long long)u << 32) | (unsigned int)(~(unsigned int)lane);
      }
      for (int kk = 2; kk <= 64; kk <<= 1) {
        for (int j = kk >> 1; j > 0; j >>= 1) {
          const unsigned int lo = __shfl_xor((unsigned int)k1, j);
          const unsigned int hi = __shfl_xor((unsigned int)(k1 >> 32), j);
          const unsigned long long kp = ((unsigned long long)hi << 32) | lo;
          const bool keep_max = (((lane & kk) == 0) == ((lane & j) == 0));
          k1 = keep_max ? (k1 >= kp ? k1 : kp) : (k1 >= kp ? kp : k1);
        }
      }
      u2[lane] = k1;
    }
    __syncthreads();
    unsigned long long* keys = u2;
    short* np1 = reinterpret_cast<short*>(csrbuf);
    if (t < 64) np1[t] = -1;
    __syncthreads();
    if (t < 7)
      np1[(int)(~(unsigned int)(keys[t] & 0xffffffffull))] = (short)t;
    __syncthreads();
    float xv7 = 0.f;
    if (w < 7) {
      const int old7 = (int)(~(unsigned int)(keys[w] & 0xffffffffull));
      xv7 = X[old7*64 + lane] * tanhf(ss1[old7]);
    }
    if (t < 64) deg[t] = 0.f;
    if (t == 0) scnt = 0;
    __syncthreads();
    if (w < 7) X[w*64 + lane] = xv7;
    for (int e = t; e < m0; e += 1024) {
      const unsigned int pr = eb[e];
      const int ns = np1[pr & 0xffff], nd2 = np1[pr >> 16];
      if (ns >= 0 && nd2 >= 0) {
        const int slot = atomicAdd(&scnt, 1);
        eb1[slot] = (unsigned int)ns | ((unsigned int)nd2 << 16);
        atomicAdd(&deg[nd2], 1.f);
      }
    }
    __syncthreads();
  }
  const int m1 = scnt;

  conv57(7, eb1, m1, cWr + 12288, cWl + 12288, cb + 192, 256);
  conv57(7, eb1, m1, cWr + 16384, cWl + 16384, cb + 256, 320);

  // ---- ph8: head ----
  if (t < 64) {
    float acc = l1b[t];
    for (int j = 0; j < 384; ++j) acc = fmaf(xsl[j], l1W[j*64 + t], acc);
    wpf[t] = fmaxf(acc, 0.f);
  }
  __syncthreads();
  if (t < 2) {
    float a2 = l2b[t];
    for (int f2 = 0; f2 < 64; ++f2) a2 = fmaf(wpf[f2], l2W[f2*2 + t], a2);
    wpf[64 + t] = a2;
  }
  __syncthreads();
  if (t < 2) {
    const float mx = fmaxf(wpf[64], wpf[65]);
    const float lse = mx + logf(expf(wpf[64]-mx) + expf(wpf[65]-mx));
    out[g*2 + t] = wpf[64 + t] - lse;
  }
}

// ============================================================================
extern "C" void kernel_launch(void* const* d_in, const int* in_sizes, int n_in,
                              void* d_out, int out_size, void* d_ws, size_t ws_size,
                              hipStream_t stream)
{
  (void)in_sizes; (void)n_in; (void)d_ws; (void)ws_size; (void)out_size;
  const float* x    = (const float*)d_in[0];
  const int*   ei   = (const int*)d_in[1];
  const float* c1Wr = (const float*)d_in[2];
  const float* c1Wl = (const float*)d_in[3];
  const float* c1b  = (const float*)d_in[4];
  const float* cWr  = (const float*)d_in[5];
  const float* cWl  = (const float*)d_in[6];
  const float* cb   = (const float*)d_in[7];
  const float* pWr  = (const float*)d_in[8];
  const float* pWl  = (const float*)d_in[9];
  const float* pb   = (const float*)d_in[10];
  const float* l1W  = (const float*)d_in[11];
  const float* l1b  = (const float*)d_in[12];
  const float* l2W  = (const float*)d_in[13];
  const float* l2b  = (const float*)d_in[14];
  float* out = (float*)d_out;
  const int* esrc = ei;
  const int* edst = ei + ETOT;

  mono<<<NB, 1024, 0, stream>>>(x, esrc, edst, c1Wr, c1Wl, c1b,
                                cWr, cWl, cb, pWr, pWl, pb,
                                l1W, l1b, l2W, l2b, out);
}

// Round 27
// 316.930 us; speedup vs baseline: 1.0476x; 1.0476x over previous
//
#include <hip/hip_runtime.h>
#include <math.h>

namespace {
constexpr int NB   = 256;          // graphs
constexpr int EPG  = 8192;         // edges per graph
constexpr int ETOT = NB * EPG;     // 2,097,152
}

// ============================================================================
// mono v3 (reverted best-known, round 24; 315.8us):
//   - whole network in one kernel, 1 block/graph, 1024 thr, ~158 KB LDS
//   - pool0 512-key bitonic in registers (shfl j<64, LDS j>=64)
//   - pool1 64-key sort in wave 0; shuffle CSR scan
//   - dual-node 8-deep LDS CSR gathers
//   - parallel global-edge-scan compaction (r25 serial walk and r26
//     register-carry both measured slower: serialization / spill storm)
// ============================================================================
__global__ __launch_bounds__(1024)
void mono(const float* __restrict__ x,
          const int* __restrict__ esrc, const int* __restrict__ edst,
          const float* __restrict__ c1Wr, const float* __restrict__ c1Wl,
          const float* __restrict__ c1b,
          const float* __restrict__ cWr, const float* __restrict__ cWl,
          const float* __restrict__ cb,
          const float* __restrict__ pwr, const float* __restrict__ pwl,
          const float* __restrict__ pb,
          const float* __restrict__ l1W, const float* __restrict__ l1b,
          const float* __restrict__ l2W, const float* __restrict__ l2b,
          float* __restrict__ out)
{
  __shared__ float zlds[512 * 64];                        // 128 KB
  __shared__ unsigned short csrbuf[EPG];                  // 16 KB
  __shared__ __align__(16) unsigned long long u2[512];    // 4 KB
  __shared__ __align__(16) float wpf[2048];               // 8 KB
  __shared__ float xsl[384];                              // 1.5 KB (JK concat)
  __shared__ int scnt;
  unsigned int* hist  = reinterpret_cast<unsigned int*>(u2);   // [0..512)
  unsigned int* start = hist + 512;                            // [512..1024)
  unsigned int* curp  = reinterpret_cast<unsigned int*>(wpf);  // scatter cursor
  const int g = blockIdx.x, t = threadIdx.x;
  const int gbase = g * 512, ebase = g * EPG;
  const int lane = t & 63, w = t >> 6;                    // 16 waves
  const int ndbase = w * 32;

  auto stage_chunk = [&](int c, int p) {
    const int xb  = p ? 8192  : 0;
    const int wrO = p ? 18432 : 16384;
    const int wlO = p ? 22528 : 20480;
    #pragma unroll
    for (int i = 0; i < 2; ++i) {            // x: 512 rows x 16 k = 2048x16B
      const int slot = t + i * 1024;
      const int r = slot >> 2, q = slot & 3;
      const float* gp = &x[(size_t)(gbase + r) * 160 + c * 16 + q * 4];
      float* lp = zlds + xb + (size_t)(i * 1024 + w * 64) * 4;
      __builtin_amdgcn_global_load_lds(
          (const __attribute__((address_space(1))) unsigned int*)gp,
          (__attribute__((address_space(3))) unsigned int*)lp, 16, 0, 0);
    }
    {
      const float* gp = &c1Wr[c * 1024 + t];
      float* lp = zlds + wrO + (size_t)(w * 64);
      __builtin_amdgcn_global_load_lds(
          (const __attribute__((address_space(1))) unsigned int*)gp,
          (__attribute__((address_space(3))) unsigned int*)lp, 4, 0, 0);
    }
    {
      const float* gp = &c1Wl[c * 1024 + t];
      float* lp = zlds + wlO + (size_t)(w * 64);
      __builtin_amdgcn_global_load_lds(
          (const __attribute__((address_space(1))) unsigned int*)gp,
          (__attribute__((address_space(3))) unsigned int*)lp, 4, 0, 0);
    }
  };

  // ---- ph1: CSR build (shuffle scan) ----
  if (t < 512) hist[t] = 0;
  if (t == 0) scnt = 0;
  __syncthreads();
  stage_chunk(0, 0);
  for (int e = t; e < EPG; e += 1024)
    atomicAdd(&hist[edst[ebase + e] - gbase], 1u);
  __syncthreads();
  {
    unsigned int v = 0;
    if (t < 512) {
      v = hist[t];
      #pragma unroll
      for (int off = 1; off < 64; off <<= 1) {
        const unsigned int up = __shfl_up(v, off);
        if (lane >= off) v += up;
      }
      if (lane == 63)
        reinterpret_cast<unsigned int*>(wpf)[1024 + w] = v;
    }
    __syncthreads();
    if (t < 512) {
      unsigned int off = 0;
      for (int i = 0; i < w; ++i)
        off += reinterpret_cast<unsigned int*>(wpf)[1024 + i];
      const unsigned int st = off + v - hist[t];
      start[t] = st;
      curp[t]  = st;
    }
    __syncthreads();
    for (int e = t; e < EPG; e += 1024) {
      const int sl = esrc[ebase + e] - gbase;
      const int dl = edst[ebase + e] - gbase;
      const unsigned int pos = atomicAdd(&curp[dl], 1u);
      csrbuf[pos] = (unsigned short)sl;
    }
  }
  __syncthreads();
  // ---- ph2: GEMM1, 2-phase pipelined ----
  float zacc[32], xla[32];
  #pragma unroll
  for (int i = 0; i < 32; ++i) { zacc[i] = 0.f; xla[i] = 0.f; }
  #pragma unroll 1
  for (int c = 0; c < 10; ++c) {
    if (c < 9) stage_chunk(c + 1, (c + 1) & 1);
    const int p   = c & 1;
    const int xb  = p ? 8192  : 0;
    const int wrO = p ? 18432 : 16384;
    const int wlO = p ? 22528 : 20480;
    #pragma unroll 1
    for (int k4 = 0; k4 < 4; ++k4) {
      const int kb = k4 * 4;
      const float wr0 = zlds[wrO + (kb+0)*64 + lane], wr1 = zlds[wrO + (kb+1)*64 + lane],
                  wr2 = zlds[wrO + (kb+2)*64 + lane], wr3 = zlds[wrO + (kb+3)*64 + lane];
      const float wl0 = zlds[wlO + (kb+0)*64 + lane], wl1 = zlds[wlO + (kb+1)*64 + lane],
                  wl2 = zlds[wlO + (kb+2)*64 + lane], wl3 = zlds[wlO + (kb+3)*64 + lane];
      #pragma unroll
      for (int i = 0; i < 32; ++i) {
        const float4 xv = *reinterpret_cast<const float4*>(
            &zlds[xb + (ndbase + i) * 16 + kb]);
        float za = zacc[i], xa = xla[i];
        za = fmaf(xv.x, wr0, za); za = fmaf(xv.y, wr1, za);
        za = fmaf(xv.z, wr2, za); za = fmaf(xv.w, wr3, za);
        xa = fmaf(xv.x, wl0, xa); xa = fmaf(xv.y, wl1, xa);
        xa = fmaf(xv.z, wl2, xa); xa = fmaf(xv.w, wl3, xa);
        zacc[i] = za; xla[i] = xa;
      }
    }
    __syncthreads();
  }
  #pragma unroll
  for (int i = 0; i < 32; ++i)
    zlds[(ndbase + i) * 64 + lane] = zacc[i];             // z1
  __syncthreads();
  // dual-node 8-deep CSR gather over LDS (per-node order = 4-chunks + tail)
  auto gather_pair = [&](float* dstacc, const float* bias_p, float& psum) {
    const float bv = bias_p[lane];
    #pragma unroll 1
    for (int i = 0; i < 16; ++i) {
      const int ndA = ndbase + i, ndB = ndbase + 16 + i;
      const unsigned int sA = start[ndA], dA = hist[ndA];
      const unsigned int sB = start[ndB], dB = hist[ndB];
      float aA0=0.f,aA1=0.f,aA2=0.f,aA3=0.f;
      float aB0=0.f,aB1=0.f,aB2=0.f,aB3=0.f;
      unsigned int jA = 0, jB = 0;
      while (jA + 4 <= dA && jB + 4 <= dB) {
        const int iA0 = csrbuf[sA+jA],   iA1 = csrbuf[sA+jA+1],
                  iA2 = csrbuf[sA+jA+2], iA3 = csrbuf[sA+jA+3];
        const int iB0 = csrbuf[sB+jB],   iB1 = csrbuf[sB+jB+1],
                  iB2 = csrbuf[sB+jB+2], iB3 = csrbuf[sB+jB+3];
        const float vA0 = zlds[iA0*64+lane], vA1 = zlds[iA1*64+lane];
        const float vA2 = zlds[iA2*64+lane], vA3 = zlds[iA3*64+lane];
        const float vB0 = zlds[iB0*64+lane], vB1 = zlds[iB1*64+lane];
        const float vB2 = zlds[iB2*64+lane], vB3 = zlds[iB3*64+lane];
        aA0 += vA0; aA1 += vA1; aA2 += vA2; aA3 += vA3;
        aB0 += vB0; aB1 += vB1; aB2 += vB2; aB3 += vB3;
        jA += 4; jB += 4;
      }
      for (; jA + 4 <= dA; jA += 4) {
        aA0 += zlds[csrbuf[sA+jA]*64+lane];   aA1 += zlds[csrbuf[sA+jA+1]*64+lane];
        aA2 += zlds[csrbuf[sA+jA+2]*64+lane]; aA3 += zlds[csrbuf[sA+jA+3]*64+lane];
      }
      for (; jB + 4 <= dB; jB += 4) {
        aB0 += zlds[csrbuf[sB+jB]*64+lane];   aB1 += zlds[csrbuf[sB+jB+1]*64+lane];
        aB2 += zlds[csrbuf[sB+jB+2]*64+lane]; aB3 += zlds[csrbuf[sB+jB+3]*64+lane];
      }
      for (; jA < dA; ++jA) aA0 += zlds[csrbuf[sA+jA]*64+lane];
      for (; jB < dB; ++jB) aB0 += zlds[csrbuf[sB+jB]*64+lane];
      float vA = ((aA0+aA1)+(aA2+aA3)) / (float)(dA > 0 ? dA : 1) + xla[i] + bv;
      float vB = ((aB0+aB1)+(aB2+aB3)) / (float)(dB > 0 ? dB : 1) + xla[16+i] + bv;
      vA = fmaxf(vA, 0.f);
      vB = fmaxf(vB, 0.f);
      dstacc[i] = vA; dstacc[16+i] = vB;
      psum += vA + vB;
    }
  };
  // ---- ph3: gather1 -> x1 ----
  {
    float psum = 0.f;
    gather_pair(zacc, c1b, psum);
    __syncthreads();
    #pragma unroll
    for (int i = 0; i < 32; ++i)
      zlds[(ndbase + i) * 64 + lane] = zacc[i];           // x1
    wpf[w * 64 + lane] = psum;
    __syncthreads();
    if (t < 64) {
      float s = 0.f;
      #pragma unroll
      for (int ww = 0; ww < 16; ++ww) s += wpf[ww*64 + t];
      xsl[0 + t] = s * (1.f/512.f);
    }
  }
  // ---- ph4: GEMM2 ----
  #pragma unroll
  for (int i = 0; i < 32; ++i) { zacc[i] = 0.f; xla[i] = 0.f; }
  {
    float* w_r = wpf;
    float* w_l = wpf + 1024;
    #pragma unroll 1
    for (int c = 0; c < 4; ++c) {
      __syncthreads();
      w_r[t] = cWr[c * 1024 + t];
      w_l[t] = cWl[c * 1024 + t];
      __syncthreads();
      #pragma unroll 1
      for (int k4 = 0; k4 < 4; ++k4) {
        const int kb = k4 * 4;
        const float wr0 = w_r[(kb+0)*64 + lane], wr1 = w_r[(kb+1)*64 + lane],
                    wr2 = w_r[(kb+2)*64 + lane], wr3 = w_r[(kb+3)*64 + lane];
        const float wl0 = w_l[(kb+0)*64 + lane], wl1 = w_l[(kb+1)*64 + lane],
                    wl2 = w_l[(kb+2)*64 + lane], wl3 = w_l[(kb+3)*64 + lane];
        #pragma unroll
        for (int i = 0; i < 32; ++i) {
          const float4 xv = *reinterpret_cast<const float4*>(
              &zlds[(ndbase + i) * 64 + c * 16 + kb]);
          float za = zacc[i], xa = xla[i];
          za = fmaf(xv.x, wr0, za); za = fmaf(xv.y, wr1, za);
          za = fmaf(xv.z, wr2, za); za = fmaf(xv.w, wr3, za);
          xa = fmaf(xv.x, wl0, xa); xa = fmaf(xv.y, wl1, xa);
          xa = fmaf(xv.z, wl2, xa); xa = fmaf(xv.w, wl3, xa);
          zacc[i] = za; xla[i] = xa;
        }
      }
    }
  }
  __syncthreads();
  #pragma unroll
  for (int i = 0; i < 32; ++i)
    zlds[(ndbase + i) * 64 + lane] = zacc[i];             // z2
  __syncthreads();
  // ---- ph5: gather2 -> x2 ----
  {
    float psum = 0.f;
    gather_pair(zacc, cb, psum);
    __syncthreads();
    #pragma unroll
    for (int i = 0; i < 32; ++i)
      zlds[(ndbase + i) * 64 + lane] = zacc[i];           // x2
    wpf[w * 64 + lane] = psum;
    __syncthreads();
    if (t < 64) {
      float s = 0.f;
      #pragma unroll
      for (int ww = 0; ww < 16; ++ww) s += wpf[ww*64 + t];
      xsl[64 + t] = s * (1.f/512.f);
    }
    __syncthreads();
  }
  // ---- ph6: pool0 ----
  {
    float* zs     = wpf;
    float* swl    = wpf + 512;
    float* sscore = wpf + 1024;
    const float pwrv = pwr[lane], pwlv = pwl[lane];
    for (int nd = w; nd < 512; nd += 16) {
      const float v = zlds[nd*64 + lane];
      float a = v * pwrv, b = v * pwlv;
      #pragma unroll
      for (int off = 32; off > 0; off >>= 1) {
        a += __shfl_xor(a, off);
        b += __shfl_xor(b, off);
      }
      if (lane == 0) { zs[nd] = a; swl[nd] = b; }
    }
    __syncthreads();
    if (t < 512) {
      const unsigned int s = start[t], d = hist[t];
      float a0 = 0.f, a1 = 0.f, a2 = 0.f, a3 = 0.f;
      unsigned int j = 0;
      for (; j + 4 <= d; j += 4) {
        a0 += zs[csrbuf[s+j]];   a1 += zs[csrbuf[s+j+1]];
        a2 += zs[csrbuf[s+j+2]]; a3 += zs[csrbuf[s+j+3]];
      }
      for (; j < d; ++j) a0 += zs[csrbuf[s+j]];
      sscore[t] = ((a0+a1)+(a2+a3)) / fmaxf((float)d, 1.f) + pb[0] + swl[t];
    }
    __syncthreads();                 // hist/start & csr dead
    unsigned long long k = 0ull;
    if (t < 512) {
      unsigned int u = __float_as_uint(sscore[t]);
      u = (u & 0x80000000u) ? ~u : (u | 0x80000000u);
      k = ((unsigned long long)u << 32) | (unsigned int)(~(unsigned int)t);
    }
    for (int kk = 2; kk <= 512; kk <<= 1) {
      for (int j = kk >> 1; j > 0; j >>= 1) {
        if (j >= 64) {
          if (t < 512) u2[t] = k;
          __syncthreads();
          unsigned long long kp = 0ull;
          if (t < 512) kp = u2[t ^ j];
          __syncthreads();
          if (t < 512) {
            const bool keep_max = (((t & kk) == 0) == ((t & j) == 0));
            k = keep_max ? (k >= kp ? k : kp) : (k >= kp ? kp : k);
          }
        } else if (t < 512) {
          const unsigned int lo = __shfl_xor((unsigned int)k, j);
          const unsigned int hi = __shfl_xor((unsigned int)(k >> 32), j);
          const unsigned long long kp = ((unsigned long long)hi << 32) | lo;
          const bool keep_max = (((t & kk) == 0) == ((t & j) == 0));
          k = keep_max ? (k >= kp ? k : kp) : (k >= kp ? kp : k);
        }
      }
    }
    if (t < 512) u2[t] = k;
    __syncthreads();
    unsigned long long* keys = u2;
    short* np = reinterpret_cast<short*>(csrbuf);
    if (t < 512) np[t] = -1;
    __syncthreads();
    if (t < 57)
      np[(int)(~(unsigned int)(keys[t] & 0xffffffffull))] = (short)t;
    __syncthreads();
    float xr[4];
    int nr = 0;
    for (int r = w * 4; r < w * 4 + 4 && r < 57; ++r) {
      const int old = (int)(~(unsigned int)(keys[r] & 0xffffffffull));
      xr[nr++] = zlds[old*64 + lane] * tanhf(sscore[old]);
    }
    if (t < 64) wpf[t] = 0.f;        // deg
    if (t == 0) scnt = 0;
    __syncthreads();
    nr = 0;
    for (int r = w * 4; r < w * 4 + 4 && r < 57; ++r)
      zlds[r*64 + lane] = xr[nr++];  // X57
    unsigned int* eb = reinterpret_cast<unsigned int*>(zlds + 16384);
    for (int e = t; e < EPG; e += 1024) {
      const int sl = esrc[ebase + e] - gbase;
      const int dl = edst[ebase + e] - gbase;
      const int ns = np[sl], nd2 = np[dl];
      if (ns >= 0 && nd2 >= 0) {
        const int slot = atomicAdd(&scnt, 1);
        eb[slot] = (unsigned int)ns | ((unsigned int)nd2 << 16);
        atomicAdd(&wpf[nd2], 1.f);
      }
    }
    __syncthreads();
  }
  const int m0 = scnt;
  // ---- ph7: tail ----
  float* X   = zlds;
  float* Z   = zlds + 4096;
  float* ACC = zlds + 8192;
  float* deg = wpf;
  unsigned int* eb  = reinterpret_cast<unsigned int*>(zlds + 16384);
  unsigned int* eb1 = reinterpret_cast<unsigned int*>(zlds + 24576);

  auto conv57 = [&](int n, const unsigned int* edges, int m,
                    const float* Wr, const float* Wl, const float* bias,
                    int xs_off) {
    float* Wfull = zlds + 12288;
    for (int i = t; i < n*64; i += 1024) ACC[i] = 0.f;
    #pragma unroll
    for (int i = 0; i < 4; ++i) Wfull[t + i*1024] = Wr[t + i*1024];
    __syncthreads();
    for (int r = w; r < n; r += 16) {
      float za = 0.f;
      for (int k = 0; k < 64; ++k)
        za = fmaf(X[r*64 + k], Wfull[k*64 + lane], za);
      Z[r*64 + lane] = za;
    }
    __syncthreads();
    for (int e = w; e < m; e += 16) {
      const unsigned int pr = edges[e];
      atomicAdd(&ACC[(pr >> 16)*64 + lane], Z[(pr & 0xffff)*64 + lane]);
    }
    #pragma unroll
    for (int i = 0; i < 4; ++i) Wfull[t + i*1024] = Wl[t + i*1024];
    __syncthreads();
    for (int i = t; i < n*64; i += 1024) {
      const int r = i >> 6, f = i & 63;
      Z[i] = ACC[i] / fmaxf(deg[r], 1.f) + bias[f];
    }
    __syncthreads();
    float psum = 0.f;
    for (int r = w; r < n; r += 16) {
      float za = Z[r*64 + lane];
      for (int k = 0; k < 64; ++k)
        za = fmaf(X[r*64 + k], Wfull[k*64 + lane], za);
      za = fmaxf(za, 0.f);
      X[r*64 + lane] = za;
      psum += za;
    }
    ACC[w*64 + lane] = psum;
    __syncthreads();
    if (t < 64) {
      float s = 0.f;
      #pragma unroll
      for (int ww = 0; ww < 16; ++ww) s += ACC[ww*64 + t];
      xsl[xs_off + t] = s / (float)n;
    }
    __syncthreads();
  };

  conv57(57, eb, m0, cWr + 4096, cWl + 4096, cb + 64, 128);
  conv57(57, eb, m0, cWr + 8192, cWl + 8192, cb + 128, 192);

  // ---- pool1: 57 -> 7 ----
  {
    float* zs1 = wpf + 1536;
    float* sw1 = wpf + 1600;
    float* ss1 = wpf + 1664;
    const float pwrv = pwr[64 + lane], pwlv = pwl[64 + lane];
    for (int r = w; r < 57; r += 16) {
      float a = X[r*64 + lane] * pwrv, b = X[r*64 + lane] * pwlv;
      #pragma unroll
      for (int off = 32; off > 0; off >>= 1) {
        a += __shfl_xor(a, off);
        b += __shfl_xor(b, off);
      }
      if (lane == 0) { zs1[r] = a; sw1[r] = b; }
    }
    if (t >= 64 && t < 128) ACC[t - 64] = 0.f;
    __syncthreads();
    for (int e = t; e < m0; e += 1024) {
      const unsigned int pr = eb[e];
      atomicAdd(&ACC[pr >> 16], zs1[pr & 0xffff]);
    }
    __syncthreads();
    if (t < 57) ss1[t] = ACC[t] / fmaxf(deg[t], 1.f) + pb[1] + sw1[t];
    __syncthreads();
    if (w == 0) {
      unsigned long long k1 = 0ull;
      if (lane < 57) {
        unsigned int u = __float_as_uint(ss1[lane]);
        u = (u & 0x80000000u) ? ~u : (u | 0x80000000u);
        k1 = ((unsigned long long)u << 32) | (unsigned int)(~(unsigned int)lane);
      }
      for (int kk = 2; kk <= 64; kk <<= 1) {
        for (int j = kk >> 1; j > 0; j >>= 1) {
          const unsigned int lo = __shfl_xor((unsigned int)k1, j);
          const unsigned int hi = __shfl_xor((unsigned int)(k1 >> 32), j);
          const unsigned long long kp = ((unsigned long long)hi << 32) | lo;
          const bool keep_max = (((lane & kk) == 0) == ((lane & j) == 0));
          k1 = keep_max ? (k1 >= kp ? k1 : kp) : (k1 >= kp ? kp : k1);
        }
      }
      u2[lane] = k1;
    }
    __syncthreads();
    unsigned long long* keys = u2;
    short* np1 = reinterpret_cast<short*>(csrbuf);
    if (t < 64) np1[t] = -1;
    __syncthreads();
    if (t < 7)
      np1[(int)(~(unsigned int)(keys[t] & 0xffffffffull))] = (short)t;
    __syncthreads();
    float xv7 = 0.f;
    if (w < 7) {
      const int old7 = (int)(~(unsigned int)(keys[w] & 0xffffffffull));
      xv7 = X[old7*64 + lane] * tanhf(ss1[old7]);
    }
    if (t < 64) deg[t] = 0.f;
    if (t == 0) scnt = 0;
    __syncthreads();
    if (w < 7) X[w*64 + lane] = xv7;
    for (int e = t; e < m0; e += 1024) {
      const unsigned int pr = eb[e];
      const int ns = np1[pr & 0xffff], nd2 = np1[pr >> 16];
      if (ns >= 0 && nd2 >= 0) {
        const int slot = atomicAdd(&scnt, 1);
        eb1[slot] = (unsigned int)ns | ((unsigned int)nd2 << 16);
        atomicAdd(&deg[nd2], 1.f);
      }
    }
    __syncthreads();
  }
  const int m1 = scnt;

  conv57(7, eb1, m1, cWr + 12288, cWl + 12288, cb + 192, 256);
  conv57(7, eb1, m1, cWr + 16384, cWl + 16384, cb + 256, 320);

  // ---- ph8: head ----
  if (t < 64) {
    float acc = l1b[t];
    for (int j = 0; j < 384; ++j) acc = fmaf(xsl[j], l1W[j*64 + t], acc);
    wpf[t] = fmaxf(acc, 0.f);
  }
  __syncthreads();
  if (t < 2) {
    float a2 = l2b[t];
    for (int f2 = 0; f2 < 64; ++f2) a2 = fmaf(wpf[f2], l2W[f2*2 + t], a2);
    wpf[64 + t] = a2;
  }
  __syncthreads();
  if (t < 2) {
    const float mx = fmaxf(wpf[64], wpf[65]);
    const float lse = mx + logf(expf(wpf[64]-mx) + expf(wpf[65]-mx));
    out[g*2 + t] = wpf[64 + t] - lse;
  }
}

// ============================================================================
extern "C" void kernel_launch(void* const* d_in, const int* in_sizes, int n_in,
                              void* d_out, int out_size, void* d_ws, size_t ws_size,
                              hipStream_t stream)
{
  (void)in_sizes; (void)n_in; (void)d_ws; (void)ws_size; (void)out_size;
  const float* x    = (const float*)d_in[0];
  const int*   ei   = (const int*)d_in[1];
  const float* c1Wr = (const float*)d_in[2];
  const float* c1Wl = (const float*)d_in[3];
  const float* c1b  = (const float*)d_in[4];
  const float* cWr  = (const float*)d_in[5];
  const float* cWl  = (const float*)d_in[6];
  const float* cb   = (const float*)d_in[7];
  const float* pWr  = (const float*)d_in[8];
  const float* pWl  = (const float*)d_in[9];
  const float* pb   = (const float*)d_in[10];
  const float* l1W  = (const float*)d_in[11];
  const float* l1b  = (const float*)d_in[12];
  const float* l2W  = (const float*)d_in[13];
  const float* l2b  = (const float*)d_in[14];
  float* out = (float*)d_out;
  const int* esrc = ei;
  const int* edst = ei + ETOT;

  mono<<<NB, 1024, 0, stream>>>(x, esrc, edst, c1Wr, c1Wl, c1b,
                                cWr, cWl, cb, pWr, pWl, pb,
                                l1W, l1b, l2W, l2b, out);
}